// Round 13
// baseline (445.026 us; speedup 1.0000x reference)
//
#include <hip/hip_runtime.h>
#include <hip/hip_bf16.h>
#include <math.h>

// ---------------------------------------------------------------------------
// ActorGNN: 4-layer GraphConv. R13 (fused v3):
//  - R12's fused gather drained the wave once per node (4 serial drains +
//    barrier) -> 1.9 TB/s vs 3.2 standalone. v3 interleaves the wave's 4
//    nodes: 1 float4 acc per node, main loop issues 4 edges x 4 nodes = 16
//    independent predicated loads per iteration (condition uniform per
//    16-lane group), loops to max trip of the 4 nodes; reductions once at
//    the end. Drains per wave: ~4 -> ~1.
//  - dense phase, CSR 2-kernel build, hi-only bf16 H, split weights: as R12.
// ---------------------------------------------------------------------------

using bfrag = __attribute__((ext_vector_type(8))) short;   // 8 bf16 (4 VGPR)
using ffrag = __attribute__((ext_vector_type(4))) float;   // 4 fp32 acc

#define BKT_SHIFT 9                 // 512 nodes per bucket
#define BKT_NODES (1 << BKT_SHIFT)
#define AGG_STRIDE 72               // shorts; 144B row pitch in LDS

__device__ __forceinline__ int load_idx32(const int* __restrict__ ei32, int is64,
                                          long long pos) {
    return is64 ? ei32[2 * pos] : ei32[pos];
}

__device__ __forceinline__ unsigned short f2b_rne(float f) {
    union { float f; unsigned u; } c;
    c.f = f;
    unsigned r = c.u + 0x7FFFu + ((c.u >> 16) & 1u);
    return (unsigned short)(r >> 16);
}

__device__ __forceinline__ float b2f(unsigned short u) {
    union { unsigned u; float f; } c;
    c.u = ((unsigned)u) << 16;
    return c.f;
}

// ---- weight prep (B^T hi/lo, 3 layers) + bktc zero + int64 detect ----
__global__ void bprep_init_kernel(
    const float* __restrict__ Ws1, const float* __restrict__ Wn1,
    const float* __restrict__ Ws2, const float* __restrict__ Wn2,
    const float* __restrict__ Ws3, const float* __restrict__ Wn3,
    unsigned short* __restrict__ bthi, unsigned short* __restrict__ btlo,
    const int* __restrict__ ei, int* __restrict__ bktc, int* __restrict__ flag) {
    if (blockIdx.x == 0) {
        bktc[threadIdx.x] = 0;
        if (threadIdx.x == 0) {
            int allz = 1;
            for (int i = 0; i < 32; ++i)
                if (ei[2 * i + 1] != 0) allz = 0;
            *flag = allz;
        }
    }
    int i = blockIdx.x * 256 + threadIdx.x;
    if (i >= 3 * 8192) return;
    int layer = i >> 13;
    int j = i & 8191;
    int n = j >> 7, k = j & 127;
    const float* Ws = layer == 0 ? Ws1 : (layer == 1 ? Ws2 : Ws3);
    const float* Wn = layer == 0 ? Wn1 : (layer == 1 ? Wn2 : Wn3);
    float v = (k < 64) ? Ws[k * 64 + n] : Wn[(k - 64) * 64 + n];
    unsigned short hi = f2b_rne(v);
    bthi[i] = hi;
    btlo[i] = f2b_rne(v - b2f(hi));
}

// x -> bf16 hi, [n][d] layout preserved
__global__ void split_x_kernel(const float4* __restrict__ in, ushort4* __restrict__ hi,
                               int n4) {
    int i = blockIdx.x * blockDim.x + threadIdx.x;
    if (i >= n4) return;
    float4 v = in[i];
    ushort4 h;
    h.x = f2b_rne(v.x); h.y = f2b_rne(v.y); h.z = f2b_rne(v.z); h.w = f2b_rne(v.w);
    hi[i] = h;
}

// ---- PassA: bin edges into dst-buckets, packed (dstLocal<<23 | src) ----
__global__ __launch_bounds__(256) void binA_kernel(
    const int* __restrict__ ei32, const int* __restrict__ flagp,
    int* __restrict__ bktCnt, unsigned* __restrict__ bins, int E, int nbkt,
    int cap, int chunksz) {
    __shared__ int cnt[256];
    __shared__ int base[256];
    int is64 = *flagp;
    int elo = blockIdx.x * chunksz;
    int ehi = min(E, elo + chunksz);
    if (elo >= E) return;
    for (int i = threadIdx.x; i < nbkt; i += 256) cnt[i] = 0;
    __syncthreads();
    for (int e = elo + (int)threadIdx.x; e < ehi; e += 256) {
        int dst = load_idx32(ei32, is64, (long long)E + e);
        atomicAdd(&cnt[dst >> BKT_SHIFT], 1);
    }
    __syncthreads();
    for (int i = threadIdx.x; i < nbkt; i += 256) {
        base[i] = atomicAdd(&bktCnt[i], cnt[i]);
        cnt[i] = 0;
    }
    __syncthreads();
    for (int e = elo + (int)threadIdx.x; e < ehi; e += 256) {
        int dst = load_idx32(ei32, is64, (long long)E + e);
        int src = load_idx32(ei32, is64, e);
        int b = dst >> BKT_SHIFT;
        int r = atomicAdd(&cnt[b], 1);
        bins[(size_t)b * cap + base[b] + r] =
            ((unsigned)(dst & (BKT_NODES - 1)) << 23) | (unsigned)src;
    }
}

// ---- bucketCSR: degree + local scan + scatter + dinv, one kernel ----
__global__ __launch_bounds__(256) void bucketCSR_kernel(
    const int* __restrict__ bktCnt, const unsigned* __restrict__ bins,
    int* __restrict__ off, int* __restrict__ offe, int* __restrict__ col,
    float* __restrict__ dinv, int N, int cap) {
    __shared__ int deg[BKT_NODES];
    __shared__ int loc[BKT_NODES];
    __shared__ int ssum[256];
    int b = blockIdx.x;
    int lo = b << BKT_SHIFT;
    int n = min(BKT_NODES, N - lo);
    for (int i = threadIdx.x; i < BKT_NODES; i += 256) deg[i] = 0;
    __syncthreads();
    int cnt = bktCnt[b];
    const unsigned* bb = bins + (size_t)b * cap;
    for (int i = threadIdx.x; i < cnt; i += 256)
        atomicAdd(&deg[bb[i] >> 23], 1);
    __syncthreads();
    int t = threadIdx.x;
    int d0 = deg[2 * t], d1 = deg[2 * t + 1];
    int s = d0 + d1;
    ssum[t] = s;
    __syncthreads();
    for (int o = 1; o < 256; o <<= 1) {
        int v = (t >= o) ? ssum[t - o] : 0;
        __syncthreads();
        ssum[t] += v;
        __syncthreads();
    }
    int excl = ssum[t] - s;
    loc[2 * t] = excl;
    loc[2 * t + 1] = excl + d0;
    __syncthreads();
    int base = b * cap;
    for (int i = threadIdx.x; i < n; i += 256) {
        int d = deg[i];
        off[lo + i] = base + loc[i];
        offe[lo + i] = base + loc[i] + d;
        dinv[lo + i] = 1.0f / fmaxf((float)d, 1.0f);
    }
    __syncthreads();
    for (int i = threadIdx.x; i < cnt; i += 256) {
        unsigned p = bb[i];
        int pos = atomicAdd(&loc[p >> 23], 1);
        col[base + pos] = (int)(p & 0x7FFFFFu);
    }
}

// ---- interleaved gather of the wave's 4 nodes into LDS (bf16) ----
// lane = g*16+t16: group g handles edge cursor+g of EACH node; per iteration
// 16 independent predicated loads (4 nodes x 4 edges) stay in flight.
__device__ __forceinline__ void gather4_nodes(
    const unsigned short* __restrict__ Hhi, const int* __restrict__ off,
    const int* __restrict__ offe, const int* __restrict__ col,
    const float* __restrict__ dinv, unsigned short* __restrict__ aggBase,
    int n0, int N, int g, int t16) {
    int e[4], en[4];
    int maxiter = 0;
#pragma unroll
    for (int i = 0; i < 4; ++i) {
        int n = n0 + i;
        if (n < N) {
            e[i] = off[n];
            en[i] = offe[n];
            int it = (en[i] - e[i] + 3) >> 2;
            if (it > maxiter) maxiter = it;
        } else {
            e[i] = 0;
            en[i] = 0;
        }
    }
    float4 a0 = make_float4(0.f, 0.f, 0.f, 0.f);
    float4 a1 = make_float4(0.f, 0.f, 0.f, 0.f);
    float4 a2 = make_float4(0.f, 0.f, 0.f, 0.f);
    float4 a3 = make_float4(0.f, 0.f, 0.f, 0.f);
    for (int it = 0; it < maxiter; ++it) {
        if (e[0] + g < en[0]) {
            int s = col[e[0] + g];
            ushort4 u = *(const ushort4*)&Hhi[(size_t)s * 64 + t16 * 4];
            a0.x += b2f(u.x); a0.y += b2f(u.y); a0.z += b2f(u.z); a0.w += b2f(u.w);
        }
        if (e[1] + g < en[1]) {
            int s = col[e[1] + g];
            ushort4 u = *(const ushort4*)&Hhi[(size_t)s * 64 + t16 * 4];
            a1.x += b2f(u.x); a1.y += b2f(u.y); a1.z += b2f(u.z); a1.w += b2f(u.w);
        }
        if (e[2] + g < en[2]) {
            int s = col[e[2] + g];
            ushort4 u = *(const ushort4*)&Hhi[(size_t)s * 64 + t16 * 4];
            a2.x += b2f(u.x); a2.y += b2f(u.y); a2.z += b2f(u.z); a2.w += b2f(u.w);
        }
        if (e[3] + g < en[3]) {
            int s = col[e[3] + g];
            ushort4 u = *(const ushort4*)&Hhi[(size_t)s * 64 + t16 * 4];
            a3.x += b2f(u.x); a3.y += b2f(u.y); a3.z += b2f(u.z); a3.w += b2f(u.w);
        }
        e[0] += 4; e[1] += 4; e[2] += 4; e[3] += 4;
    }
    // cross-group reduction + LDS write, one node at a time
#pragma unroll
    for (int i = 0; i < 4; ++i) {
        float4 acc = (i == 0) ? a0 : (i == 1) ? a1 : (i == 2) ? a2 : a3;
#pragma unroll
        for (int msk = 16; msk <= 32; msk <<= 1) {
            acc.x += __shfl_xor(acc.x, msk, 64);
            acc.y += __shfl_xor(acc.y, msk, 64);
            acc.z += __shfl_xor(acc.z, msk, 64);
            acc.w += __shfl_xor(acc.w, msk, 64);
        }
        if (g == 0) {
            int n = n0 + i;
            float di = (n < N) ? dinv[n] : 0.f;
            ushort4 h;
            h.x = f2b_rne(acc.x * di);
            h.y = f2b_rne(acc.y * di);
            h.z = f2b_rne(acc.z * di);
            h.w = f2b_rne(acc.w * di);
            *(ushort4*)&aggBase[i * AGG_STRIDE + t16 * 4] = h;
        }
    }
}

// ---- fused layer v3: block = 4 waves, 16 nodes; wave w gathers nodes
// w*4..w*4+3 (interleaved), then computes out-cols w*16..w*16+15 via MFMA.
__global__ __launch_bounds__(256) void layer_fused_kernel(
    const unsigned short* __restrict__ Hhi, const int* __restrict__ off,
    const int* __restrict__ offe, const int* __restrict__ col,
    const float* __restrict__ dinv,
    const unsigned short* __restrict__ Bthi, const unsigned short* __restrict__ Btlo,
    const float* __restrict__ b, unsigned short* __restrict__ Dhi, int N) {
    __shared__ unsigned short aggL[16 * AGG_STRIDE];
    int wave = threadIdx.x >> 6;
    int lane = threadIdx.x & 63;
    int g = lane >> 4;
    int t16 = lane & 15;
    int n0 = blockIdx.x * 16;
    gather4_nodes(Hhi, off, offe, col, dinv, aggL + wave * 4 * AGG_STRIDE,
                  n0 + wave * 4, N, g, t16);
    __syncthreads();
    int m = t16, quad = g;
    int nr = n0 + m;
    if (nr > N - 1) nr = N - 1;
    const unsigned short* hrow = Hhi + (size_t)nr * 64 + quad * 8;
    bfrag ah[4];
    ah[0] = *(const bfrag*)(hrow);
    ah[1] = *(const bfrag*)(hrow + 32);
    ah[2] = *(const bfrag*)&aggL[m * AGG_STRIDE + quad * 8];
    ah[3] = *(const bfrag*)&aggL[m * AGG_STRIDE + 32 + quad * 8];
    int oc = wave * 16 + m;  // out col
    float bl = b[oc];
    ffrag acc = {bl, bl, bl, bl};
#pragma unroll
    for (int c = 0; c < 4; ++c) {
        bfrag bh = *(const bfrag*)(Bthi + (size_t)oc * 128 + c * 32 + quad * 8);
        bfrag bw = *(const bfrag*)(Btlo + (size_t)oc * 128 + c * 32 + quad * 8);
        acc = __builtin_amdgcn_mfma_f32_16x16x32_bf16(ah[c], bh, acc, 0, 0, 0);
        acc = __builtin_amdgcn_mfma_f32_16x16x32_bf16(ah[c], bw, acc, 0, 0, 0);
    }
#pragma unroll
    for (int r = 0; r < 4; ++r) {
        int node = n0 + quad * 4 + r;
        if (node < N)
            Dhi[(size_t)node * 64 + oc] = f2b_rne(fmaxf(acc[r], 0.f));
    }
}

// ---- fused layer 3 + layer-4 pre-transform ----
__global__ __launch_bounds__(256) void layer_fused_last_kernel(
    const unsigned short* __restrict__ Hhi, const int* __restrict__ off,
    const int* __restrict__ offe, const int* __restrict__ col,
    const float* __restrict__ dinv,
    const unsigned short* __restrict__ Bthi, const unsigned short* __restrict__ Btlo,
    const float* __restrict__ b, const float* __restrict__ Ws4,
    const float* __restrict__ Wn4, float* __restrict__ sbuf,
    float* __restrict__ gbuf, int N) {
    __shared__ unsigned short aggL[16 * AGG_STRIDE];
    __shared__ float sPart[4][16];
    __shared__ float gPart[4][16];
    int wave = threadIdx.x >> 6;
    int lane = threadIdx.x & 63;
    int g = lane >> 4;
    int t16 = lane & 15;
    int n0 = blockIdx.x * 16;
    gather4_nodes(Hhi, off, offe, col, dinv, aggL + wave * 4 * AGG_STRIDE,
                  n0 + wave * 4, N, g, t16);
    __syncthreads();
    int m = t16, quad = g;
    int nr = n0 + m;
    if (nr > N - 1) nr = N - 1;
    const unsigned short* hrow = Hhi + (size_t)nr * 64 + quad * 8;
    bfrag ah[4];
    ah[0] = *(const bfrag*)(hrow);
    ah[1] = *(const bfrag*)(hrow + 32);
    ah[2] = *(const bfrag*)&aggL[m * AGG_STRIDE + quad * 8];
    ah[3] = *(const bfrag*)&aggL[m * AGG_STRIDE + 32 + quad * 8];
    int oc = wave * 16 + m;
    float bl = b[oc];
    ffrag acc = {bl, bl, bl, bl};
#pragma unroll
    for (int c = 0; c < 4; ++c) {
        bfrag bh = *(const bfrag*)(Bthi + (size_t)oc * 128 + c * 32 + quad * 8);
        bfrag bw = *(const bfrag*)(Btlo + (size_t)oc * 128 + c * 32 + quad * 8);
        acc = __builtin_amdgcn_mfma_f32_16x16x32_bf16(ah[c], bh, acc, 0, 0, 0);
        acc = __builtin_amdgcn_mfma_f32_16x16x32_bf16(ah[c], bw, acc, 0, 0, 0);
    }
    float w4s = Ws4[oc], w4n = Wn4[oc];
#pragma unroll
    for (int r = 0; r < 4; ++r) {
        float v = fmaxf(acc[r], 0.f);
        float ps = v * w4s;
        float pg = v * w4n;
#pragma unroll
        for (int mask = 1; mask <= 8; mask <<= 1) {
            ps += __shfl_xor(ps, mask, 64);
            pg += __shfl_xor(pg, mask, 64);
        }
        if (m == 0) {
            sPart[wave][quad * 4 + r] = ps;
            gPart[wave][quad * 4 + r] = pg;
        }
    }
    __syncthreads();
    if (threadIdx.x < 16) {
        int node = n0 + threadIdx.x;
        if (node < N) {
            float s = sPart[0][threadIdx.x] + sPart[1][threadIdx.x] +
                      sPart[2][threadIdx.x] + sPart[3][threadIdx.x];
            float gg = gPart[0][threadIdx.x] + gPart[1][threadIdx.x] +
                       gPart[2][threadIdx.x] + gPart[3][threadIdx.x];
            sbuf[node] = s;
            gbuf[node] = gg;
        }
    }
}

// thread per node: scalar CSR gather of g (400 KB, L2-resident) + sigmoid
__global__ void final_kernel(const float* __restrict__ s, const float* __restrict__ dinv,
                             const float* __restrict__ g, const int* __restrict__ off,
                             const int* __restrict__ offe, const int* __restrict__ col,
                             const float* __restrict__ b4, float* __restrict__ out, int N) {
    int n = blockIdx.x * blockDim.x + threadIdx.x;
    if (n >= N) return;
    float a = 0.f;
    int e = off[n], end = offe[n];
    for (; e < end; ++e) a += g[col[e]];
    float z = s[n] + dinv[n] * a + b4[0];
    out[n] = 1.0f / (1.0f + expf(-z));
}

static inline int cdiv(long long a, long long b) { return (int)((a + b - 1) / b); }

extern "C" void kernel_launch(void* const* d_in, const int* in_sizes, int n_in,
                              void* d_out, int out_size, void* d_ws, size_t ws_size,
                              hipStream_t stream) {
    const float* x   = (const float*)d_in[0];
    const int*   ei  = (const int*)d_in[1];
    const float* Ws1 = (const float*)d_in[2];
    const float* Wn1 = (const float*)d_in[3];
    const float* b1  = (const float*)d_in[4];
    const float* Ws2 = (const float*)d_in[5];
    const float* Wn2 = (const float*)d_in[6];
    const float* b2  = (const float*)d_in[7];
    const float* Ws3 = (const float*)d_in[8];
    const float* Wn3 = (const float*)d_in[9];
    const float* b3  = (const float*)d_in[10];
    const float* Ws4 = (const float*)d_in[11];
    const float* Wn4 = (const float*)d_in[12];
    const float* b4  = (const float*)d_in[13];
    float* out = (float*)d_out;

    const int N = in_sizes[0] / 64;
    const int E = in_sizes[1] / 2;

    const int nbkt = cdiv(N, BKT_NODES);                 // <=256
    const int cap  = E / nbkt + E / nbkt / 8 + 64;       // ~12.5% margin

    // workspace layout
    unsigned* bins = (unsigned*)d_ws;                    // nbkt*cap
    int* col = (int*)(bins + (size_t)nbkt * cap);        // nbkt*cap (bucket-local)
    unsigned short* HhiA = (unsigned short*)(col + (size_t)nbkt * cap);  // N*64
    unsigned short* HhiB = HhiA + (size_t)N * 64;        // N*64
    unsigned short* Bth  = HhiB + (size_t)N * 64;        // 3*8192
    unsigned short* Btl  = Bth + 3 * 8192;               // 3*8192
    float* dinv = (float*)(Btl + 3 * 8192);              // N
    float* sbuf = dinv + N;                              // N
    float* gbuf = sbuf + N;                              // N
    int*   off  = (int*)(gbuf + N);                      // N
    int*   offe = off + N;                               // N
    int*   bktc = offe + N;                              // 256
    int*   flag = bktc + 256;                            // 1

    const int BT = 256;
    const int gridN  = cdiv(N, BT);
    const int gridL  = cdiv(N, 16);                      // 16 nodes/block
    const int binBlocks = 512;
    const int chunksz = cdiv(E, binBlocks);

    // ---- prep: weights + init, x->bf16 ----
    bprep_init_kernel<<<96, BT, 0, stream>>>(Ws1, Wn1, Ws2, Wn2, Ws3, Wn3,
                                             Bth, Btl, ei, bktc, flag);
    split_x_kernel<<<cdiv((long long)N * 16, BT), BT, 0, stream>>>(
        (const float4*)x, (ushort4*)HhiA, N * 16);

    // ---- CSR build: 2 kernels ----
    binA_kernel<<<binBlocks, BT, 0, stream>>>(ei, flag, bktc, bins, E, nbkt, cap, chunksz);
    bucketCSR_kernel<<<nbkt, BT, 0, stream>>>(bktc, bins, off, offe, col, dinv, N, cap);

    // ---- layers 1-3 (fused gather+dense v3) ----
    layer_fused_kernel<<<gridL, BT, 0, stream>>>(HhiA, off, offe, col, dinv,
                                                 Bth, Btl, b1, HhiB, N);
    layer_fused_kernel<<<gridL, BT, 0, stream>>>(HhiB, off, offe, col, dinv,
                                                 Bth + 8192, Btl + 8192, b2, HhiA, N);
    layer_fused_last_kernel<<<gridL, BT, 0, stream>>>(HhiA, off, offe, col, dinv,
                                                      Bth + 16384, Btl + 16384, b3,
                                                      Ws4, Wn4, sbuf, gbuf, N);

    // ---- layer 4 (64->1): scalar CSR gather + sigmoid ----
    final_kernel<<<gridN, BT, 0, stream>>>(sbuf, dinv, gbuf, off, offe, col, b4, out, N);
}

// Round 14
// 415.853 us; speedup vs baseline: 1.0702x; 1.0702x over previous
//
#include <hip/hip_runtime.h>
#include <hip/hip_bf16.h>
#include <math.h>

// ---------------------------------------------------------------------------
// ActorGNN: 4-layer GraphConv. R14: best-of-both assembly.
//  - Layers SPLIT again (R13 post-mortem: fusion caps gather at 1.9 TB/s via
//    per-node drains + barrier imbalance; split gather runs 3.2 TB/s, dense
//    MFMA 18us — both individually measured in R10).
//  - CSR build kept at R11/R12's 2-kernel form (binA + bucketCSR, bucket-
//    local col regions) — measured ~40us vs R10's 7-kernel ~85us.
//  - prep fused (bprep_init, split_x), layer-3 dense fuses layer-4 pre.
//  - 11 dispatches. hi-only bf16 H; weights hi/lo split (3-term via 2 MFMA).
// ---------------------------------------------------------------------------

using bfrag = __attribute__((ext_vector_type(8))) short;   // 8 bf16 (4 VGPR)
using ffrag = __attribute__((ext_vector_type(4))) float;   // 4 fp32 acc

#define BKT_SHIFT 9                 // 512 nodes per bucket
#define BKT_NODES (1 << BKT_SHIFT)

__device__ __forceinline__ int load_idx32(const int* __restrict__ ei32, int is64,
                                          long long pos) {
    return is64 ? ei32[2 * pos] : ei32[pos];
}

__device__ __forceinline__ unsigned short f2b_rne(float f) {
    union { float f; unsigned u; } c;
    c.f = f;
    unsigned r = c.u + 0x7FFFu + ((c.u >> 16) & 1u);
    return (unsigned short)(r >> 16);
}

__device__ __forceinline__ float b2f(unsigned short u) {
    union { unsigned u; float f; } c;
    c.u = ((unsigned)u) << 16;
    return c.f;
}

// ---- weight prep (B^T hi/lo, 3 layers) + bktc zero + int64 detect ----
__global__ void bprep_init_kernel(
    const float* __restrict__ Ws1, const float* __restrict__ Wn1,
    const float* __restrict__ Ws2, const float* __restrict__ Wn2,
    const float* __restrict__ Ws3, const float* __restrict__ Wn3,
    unsigned short* __restrict__ bthi, unsigned short* __restrict__ btlo,
    const int* __restrict__ ei, int* __restrict__ bktc, int* __restrict__ flag) {
    if (blockIdx.x == 0) {
        bktc[threadIdx.x] = 0;
        if (threadIdx.x == 0) {
            int allz = 1;
            for (int i = 0; i < 32; ++i)
                if (ei[2 * i + 1] != 0) allz = 0;
            *flag = allz;
        }
    }
    int i = blockIdx.x * 256 + threadIdx.x;
    if (i >= 3 * 8192) return;
    int layer = i >> 13;
    int j = i & 8191;
    int n = j >> 7, k = j & 127;
    const float* Ws = layer == 0 ? Ws1 : (layer == 1 ? Ws2 : Ws3);
    const float* Wn = layer == 0 ? Wn1 : (layer == 1 ? Wn2 : Wn3);
    float v = (k < 64) ? Ws[k * 64 + n] : Wn[(k - 64) * 64 + n];
    unsigned short hi = f2b_rne(v);
    bthi[i] = hi;
    btlo[i] = f2b_rne(v - b2f(hi));
}

// x -> bf16 hi, [n][d] layout preserved
__global__ void split_x_kernel(const float4* __restrict__ in, ushort4* __restrict__ hi,
                               int n4) {
    int i = blockIdx.x * blockDim.x + threadIdx.x;
    if (i >= n4) return;
    float4 v = in[i];
    ushort4 h;
    h.x = f2b_rne(v.x); h.y = f2b_rne(v.y); h.z = f2b_rne(v.z); h.w = f2b_rne(v.w);
    hi[i] = h;
}

// ---- PassA: bin edges into dst-buckets, packed (dstLocal<<23 | src) ----
__global__ __launch_bounds__(256) void binA_kernel(
    const int* __restrict__ ei32, const int* __restrict__ flagp,
    int* __restrict__ bktCnt, unsigned* __restrict__ bins, int E, int nbkt,
    int cap, int chunksz) {
    __shared__ int cnt[256];
    __shared__ int base[256];
    int is64 = *flagp;
    int elo = blockIdx.x * chunksz;
    int ehi = min(E, elo + chunksz);
    if (elo >= E) return;
    for (int i = threadIdx.x; i < nbkt; i += 256) cnt[i] = 0;
    __syncthreads();
    for (int e = elo + (int)threadIdx.x; e < ehi; e += 256) {
        int dst = load_idx32(ei32, is64, (long long)E + e);
        atomicAdd(&cnt[dst >> BKT_SHIFT], 1);
    }
    __syncthreads();
    for (int i = threadIdx.x; i < nbkt; i += 256) {
        base[i] = atomicAdd(&bktCnt[i], cnt[i]);
        cnt[i] = 0;
    }
    __syncthreads();
    for (int e = elo + (int)threadIdx.x; e < ehi; e += 256) {
        int dst = load_idx32(ei32, is64, (long long)E + e);
        int src = load_idx32(ei32, is64, e);
        int b = dst >> BKT_SHIFT;
        int r = atomicAdd(&cnt[b], 1);
        bins[(size_t)b * cap + base[b] + r] =
            ((unsigned)(dst & (BKT_NODES - 1)) << 23) | (unsigned)src;
    }
}

// ---- bucketCSR: degree + local scan + scatter + dinv, one kernel ----
__global__ __launch_bounds__(256) void bucketCSR_kernel(
    const int* __restrict__ bktCnt, const unsigned* __restrict__ bins,
    int* __restrict__ off, int* __restrict__ offe, int* __restrict__ col,
    float* __restrict__ dinv, int N, int cap) {
    __shared__ int deg[BKT_NODES];
    __shared__ int loc[BKT_NODES];
    __shared__ int ssum[256];
    int b = blockIdx.x;
    int lo = b << BKT_SHIFT;
    int n = min(BKT_NODES, N - lo);
    for (int i = threadIdx.x; i < BKT_NODES; i += 256) deg[i] = 0;
    __syncthreads();
    int cnt = bktCnt[b];
    const unsigned* bb = bins + (size_t)b * cap;
    for (int i = threadIdx.x; i < cnt; i += 256)
        atomicAdd(&deg[bb[i] >> 23], 1);
    __syncthreads();
    int t = threadIdx.x;
    int d0 = deg[2 * t], d1 = deg[2 * t + 1];
    int s = d0 + d1;
    ssum[t] = s;
    __syncthreads();
    for (int o = 1; o < 256; o <<= 1) {
        int v = (t >= o) ? ssum[t - o] : 0;
        __syncthreads();
        ssum[t] += v;
        __syncthreads();
    }
    int excl = ssum[t] - s;
    loc[2 * t] = excl;
    loc[2 * t + 1] = excl + d0;
    __syncthreads();
    int base = b * cap;
    for (int i = threadIdx.x; i < n; i += 256) {
        int d = deg[i];
        off[lo + i] = base + loc[i];
        offe[lo + i] = base + loc[i] + d;
        dinv[lo + i] = 1.0f / fmaxf((float)d, 1.0f);
    }
    __syncthreads();
    for (int i = threadIdx.x; i < cnt; i += 256) {
        unsigned p = bb[i];
        int pos = atomicAdd(&loc[p >> 23], 1);
        col[base + pos] = (int)(p & 0x7FFFFFu);
    }
}

// wave per node; lane = g*16 + t: edge-group g (0..3), dims t*4..t*4+3.
// Reads bf16-hi rows (128B); emits mean-scaled agg as bf16 hi.
// Proven 52us @ 3.2 TB/s (R9/R10).
__global__ __launch_bounds__(256) void gather64_b16_kernel(
    const unsigned short* __restrict__ hb, const int* __restrict__ off,
    const int* __restrict__ offe, const int* __restrict__ col,
    const float* __restrict__ dinv, unsigned short* __restrict__ ghi, int N) {
    int wave = threadIdx.x >> 6;
    int lane = threadIdx.x & 63;
    int g = lane >> 4;
    int t = lane & 15;
    int n = blockIdx.x * 4 + wave;
    if (n >= N) return;
    int e = off[n], end = offe[n];
    float4 a0 = make_float4(0.f, 0.f, 0.f, 0.f);
    float4 a1 = make_float4(0.f, 0.f, 0.f, 0.f);
    float4 a2 = make_float4(0.f, 0.f, 0.f, 0.f);
    float4 a3 = make_float4(0.f, 0.f, 0.f, 0.f);
    for (; e + 16 <= end; e += 16) {
        int s0 = col[e + g];
        int s1 = col[e + 4 + g];
        int s2 = col[e + 8 + g];
        int s3 = col[e + 12 + g];
        ushort4 u0 = *(const ushort4*)&hb[(size_t)s0 * 64 + t * 4];
        ushort4 u1 = *(const ushort4*)&hb[(size_t)s1 * 64 + t * 4];
        ushort4 u2 = *(const ushort4*)&hb[(size_t)s2 * 64 + t * 4];
        ushort4 u3 = *(const ushort4*)&hb[(size_t)s3 * 64 + t * 4];
        a0.x += b2f(u0.x); a0.y += b2f(u0.y); a0.z += b2f(u0.z); a0.w += b2f(u0.w);
        a1.x += b2f(u1.x); a1.y += b2f(u1.y); a1.z += b2f(u1.z); a1.w += b2f(u1.w);
        a2.x += b2f(u2.x); a2.y += b2f(u2.y); a2.z += b2f(u2.z); a2.w += b2f(u2.w);
        a3.x += b2f(u3.x); a3.y += b2f(u3.y); a3.z += b2f(u3.z); a3.w += b2f(u3.w);
    }
    for (; e + 8 <= end; e += 8) {
        int s0 = col[e + g];
        int s1 = col[e + 4 + g];
        ushort4 u0 = *(const ushort4*)&hb[(size_t)s0 * 64 + t * 4];
        ushort4 u1 = *(const ushort4*)&hb[(size_t)s1 * 64 + t * 4];
        a0.x += b2f(u0.x); a0.y += b2f(u0.y); a0.z += b2f(u0.z); a0.w += b2f(u0.w);
        a1.x += b2f(u1.x); a1.y += b2f(u1.y); a1.z += b2f(u1.z); a1.w += b2f(u1.w);
    }
    for (; e < end; e += 4) {
        if (e + g < end) {
            int s0 = col[e + g];
            ushort4 u0 = *(const ushort4*)&hb[(size_t)s0 * 64 + t * 4];
            a2.x += b2f(u0.x); a2.y += b2f(u0.y); a2.z += b2f(u0.z); a2.w += b2f(u0.w);
        }
    }
    float4 acc;
    acc.x = (a0.x + a1.x) + (a2.x + a3.x);
    acc.y = (a0.y + a1.y) + (a2.y + a3.y);
    acc.z = (a0.z + a1.z) + (a2.z + a3.z);
    acc.w = (a0.w + a1.w) + (a2.w + a3.w);
#pragma unroll
    for (int m = 16; m <= 32; m <<= 1) {
        acc.x += __shfl_xor(acc.x, m, 64);
        acc.y += __shfl_xor(acc.y, m, 64);
        acc.z += __shfl_xor(acc.z, m, 64);
        acc.w += __shfl_xor(acc.w, m, 64);
    }
    if (g == 0) {
        float di = dinv[n];
        ushort4 h;
        h.x = f2b_rne(acc.x * di);
        h.y = f2b_rne(acc.y * di);
        h.z = f2b_rne(acc.z * di);
        h.w = f2b_rne(acc.w * di);
        *(ushort4*)&ghi[(size_t)n * 64 + t * 4] = h;
    }
}

// MFMA dense: D = relu([h|agg] @ [Ws;Wn] + b). hi-only inputs; weights hi/lo.
// A-frag: m=lane&15, k=quad*8+j. B-frag: n=lane&15 (Bt[n][k]).
// C/D: col=lane&15, row=quad*4+reg. Proven ~18us (R10).
__global__ __launch_bounds__(256) void dense_mfma_kernel(
    const unsigned short* __restrict__ Hhi, const unsigned short* __restrict__ Ghi,
    const unsigned short* __restrict__ Bthi, const unsigned short* __restrict__ Btlo,
    const float* __restrict__ b, unsigned short* __restrict__ Dhi, int N) {
    int lane = threadIdx.x & 63;
    int m = lane & 15, quad = lane >> 4;
    int wid = (blockIdx.x * blockDim.x + threadIdx.x) >> 6;
    int nw = (gridDim.x * blockDim.x) >> 6;
    bfrag bhi[4][4];
#pragma unroll
    for (int t = 0; t < 4; ++t)
#pragma unroll
        for (int c = 0; c < 4; ++c)
            bhi[t][c] = *(const bfrag*)(Bthi + (size_t)(t * 16 + m) * 128 + c * 32 + quad * 8);
    float bl[4];
#pragma unroll
    for (int t = 0; t < 4; ++t) bl[t] = b[t * 16 + m];
    int ngroups = (N + 15) >> 4;
    for (int g = wid; g < ngroups; g += nw) {
        int n0 = g << 4;
        int nr = n0 + m;
        if (nr > N - 1) nr = N - 1;
        const unsigned short* hrow = Hhi + (size_t)nr * 64 + quad * 8;
        const unsigned short* grow = Ghi + (size_t)nr * 64 + quad * 8;
        bfrag ah[4];
        ah[0] = *(const bfrag*)(hrow);
        ah[1] = *(const bfrag*)(hrow + 32);
        ah[2] = *(const bfrag*)(grow);
        ah[3] = *(const bfrag*)(grow + 32);
#pragma unroll
        for (int t = 0; t < 4; ++t) {
            ffrag acc = {bl[t], bl[t], bl[t], bl[t]};
#pragma unroll
            for (int c = 0; c < 4; ++c) {
                bfrag blo = *(const bfrag*)(Btlo + (size_t)(t * 16 + m) * 128 + c * 32 + quad * 8);
                acc = __builtin_amdgcn_mfma_f32_16x16x32_bf16(ah[c], bhi[t][c], acc, 0, 0, 0);
                acc = __builtin_amdgcn_mfma_f32_16x16x32_bf16(ah[c], blo, acc, 0, 0, 0);
            }
#pragma unroll
            for (int r = 0; r < 4; ++r) {
                int node = n0 + quad * 4 + r;
                if (node < N)
                    Dhi[(size_t)node * 64 + t * 16 + m] = f2b_rne(fmaxf(acc[r], 0.f));
            }
        }
    }
}

// Layer-3 dense with fused layer-4 pre-transform: h3 = relu(z3) stays in fp32
// accs; epilogue computes s = h3·Ws4, g = h3·Wn4 via intra-quad shfl_xor.
__global__ __launch_bounds__(256) void dense_mfma_last_kernel(
    const unsigned short* __restrict__ Hhi, const unsigned short* __restrict__ Ghi,
    const unsigned short* __restrict__ Bthi, const unsigned short* __restrict__ Btlo,
    const float* __restrict__ b, const float* __restrict__ Ws4,
    const float* __restrict__ Wn4, float* __restrict__ sbuf,
    float* __restrict__ gbuf, int N) {
    int lane = threadIdx.x & 63;
    int m = lane & 15, quad = lane >> 4;
    int wid = (blockIdx.x * blockDim.x + threadIdx.x) >> 6;
    int nw = (gridDim.x * blockDim.x) >> 6;
    bfrag bhi[4][4];
#pragma unroll
    for (int t = 0; t < 4; ++t)
#pragma unroll
        for (int c = 0; c < 4; ++c)
            bhi[t][c] = *(const bfrag*)(Bthi + (size_t)(t * 16 + m) * 128 + c * 32 + quad * 8);
    float bl[4], w4s[4], w4n[4];
#pragma unroll
    for (int t = 0; t < 4; ++t) {
        bl[t] = b[t * 16 + m];
        w4s[t] = Ws4[t * 16 + m];
        w4n[t] = Wn4[t * 16 + m];
    }
    int ngroups = (N + 15) >> 4;
    for (int g = wid; g < ngroups; g += nw) {
        int n0 = g << 4;
        int nr = n0 + m;
        if (nr > N - 1) nr = N - 1;
        const unsigned short* hrow = Hhi + (size_t)nr * 64 + quad * 8;
        const unsigned short* grow = Ghi + (size_t)nr * 64 + quad * 8;
        bfrag ah[4];
        ah[0] = *(const bfrag*)(hrow);
        ah[1] = *(const bfrag*)(hrow + 32);
        ah[2] = *(const bfrag*)(grow);
        ah[3] = *(const bfrag*)(grow + 32);
        ffrag accs[4];
#pragma unroll
        for (int t = 0; t < 4; ++t) {
            ffrag acc = {bl[t], bl[t], bl[t], bl[t]};
#pragma unroll
            for (int c = 0; c < 4; ++c) {
                bfrag blo = *(const bfrag*)(Btlo + (size_t)(t * 16 + m) * 128 + c * 32 + quad * 8);
                acc = __builtin_amdgcn_mfma_f32_16x16x32_bf16(ah[c], bhi[t][c], acc, 0, 0, 0);
                acc = __builtin_amdgcn_mfma_f32_16x16x32_bf16(ah[c], blo, acc, 0, 0, 0);
            }
            accs[t] = acc;
        }
#pragma unroll
        for (int r = 0; r < 4; ++r) {
            float ps = 0.f, pg = 0.f;
#pragma unroll
            for (int t = 0; t < 4; ++t) {
                float v = fmaxf(accs[t][r], 0.f);
                ps = fmaf(v, w4s[t], ps);
                pg = fmaf(v, w4n[t], pg);
            }
#pragma unroll
            for (int mask = 1; mask <= 8; mask <<= 1) {
                ps += __shfl_xor(ps, mask, 64);
                pg += __shfl_xor(pg, mask, 64);
            }
            int node = n0 + quad * 4 + r;
            if (m == 0 && node < N) {
                sbuf[node] = ps;
                gbuf[node] = pg;
            }
        }
    }
}

// thread per node: scalar CSR gather of g (400 KB, L2-resident) + sigmoid
__global__ void final_kernel(const float* __restrict__ s, const float* __restrict__ dinv,
                             const float* __restrict__ g, const int* __restrict__ off,
                             const int* __restrict__ offe, const int* __restrict__ col,
                             const float* __restrict__ b4, float* __restrict__ out, int N) {
    int n = blockIdx.x * blockDim.x + threadIdx.x;
    if (n >= N) return;
    float a = 0.f;
    int e = off[n], end = offe[n];
    for (; e < end; ++e) a += g[col[e]];
    float z = s[n] + dinv[n] * a + b4[0];
    out[n] = 1.0f / (1.0f + expf(-z));
}

static inline int cdiv(long long a, long long b) { return (int)((a + b - 1) / b); }

extern "C" void kernel_launch(void* const* d_in, const int* in_sizes, int n_in,
                              void* d_out, int out_size, void* d_ws, size_t ws_size,
                              hipStream_t stream) {
    const float* x   = (const float*)d_in[0];
    const int*   ei  = (const int*)d_in[1];
    const float* Ws1 = (const float*)d_in[2];
    const float* Wn1 = (const float*)d_in[3];
    const float* b1  = (const float*)d_in[4];
    const float* Ws2 = (const float*)d_in[5];
    const float* Wn2 = (const float*)d_in[6];
    const float* b2  = (const float*)d_in[7];
    const float* Ws3 = (const float*)d_in[8];
    const float* Wn3 = (const float*)d_in[9];
    const float* b3  = (const float*)d_in[10];
    const float* Ws4 = (const float*)d_in[11];
    const float* Wn4 = (const float*)d_in[12];
    const float* b4  = (const float*)d_in[13];
    float* out = (float*)d_out;

    const int N = in_sizes[0] / 64;
    const int E = in_sizes[1] / 2;

    const int nbkt = cdiv(N, BKT_NODES);                 // <=256
    const int cap  = E / nbkt + E / nbkt / 8 + 64;       // ~12.5% margin

    // workspace layout
    unsigned* bins = (unsigned*)d_ws;                    // nbkt*cap
    int* col = (int*)(bins + (size_t)nbkt * cap);        // nbkt*cap (bucket-local)
    unsigned short* HhiA = (unsigned short*)(col + (size_t)nbkt * cap);  // N*64
    unsigned short* HhiB = HhiA + (size_t)N * 64;        // N*64
    unsigned short* Ghi  = HhiB + (size_t)N * 64;        // N*64
    unsigned short* Bth  = Ghi + (size_t)N * 64;         // 3*8192
    unsigned short* Btl  = Bth + 3 * 8192;               // 3*8192
    float* dinv = (float*)(Btl + 3 * 8192);              // N
    float* sbuf = dinv + N;                              // N
    float* gbuf = sbuf + N;                              // N
    int*   off  = (int*)(gbuf + N);                      // N
    int*   offe = off + N;                               // N
    int*   bktc = offe + N;                              // 256
    int*   flag = bktc + 256;                            // 1

    const int BT = 256;
    const int gridN  = cdiv(N, BT);
    const int gridNd = cdiv(N, 4);                       // gather: wave/node
    const int gridMM = cdiv(cdiv(N, 16), 4);             // dense: 4 waves/block
    const int binBlocks = 512;
    const int chunksz = cdiv(E, binBlocks);

    // ---- prep: weights + init, x->bf16 ----
    bprep_init_kernel<<<96, BT, 0, stream>>>(Ws1, Wn1, Ws2, Wn2, Ws3, Wn3,
                                             Bth, Btl, ei, bktc, flag);
    split_x_kernel<<<cdiv((long long)N * 16, BT), BT, 0, stream>>>(
        (const float4*)x, (ushort4*)HhiA, N * 16);

    // ---- CSR build: 2 kernels ----
    binA_kernel<<<binBlocks, BT, 0, stream>>>(ei, flag, bktc, bins, E, nbkt, cap, chunksz);
    bucketCSR_kernel<<<nbkt, BT, 0, stream>>>(bktc, bins, off, offe, col, dinv, N, cap);

    // ---- layer 1 ----
    gather64_b16_kernel<<<gridNd, BT, 0, stream>>>(HhiA, off, offe, col, dinv, Ghi, N);
    dense_mfma_kernel<<<gridMM, BT, 0, stream>>>(HhiA, Ghi, Bth, Btl, b1, HhiB, N);

    // ---- layer 2 ----
    gather64_b16_kernel<<<gridNd, BT, 0, stream>>>(HhiB, off, offe, col, dinv, Ghi, N);
    dense_mfma_kernel<<<gridMM, BT, 0, stream>>>(HhiB, Ghi, Bth + 8192, Btl + 8192,
                                                 b2, HhiA, N);

    // ---- layer 3 + fused layer-4 pre-transform ----
    gather64_b16_kernel<<<gridNd, BT, 0, stream>>>(HhiA, off, offe, col, dinv, Ghi, N);
    dense_mfma_last_kernel<<<gridMM, BT, 0, stream>>>(HhiA, Ghi, Bth + 16384,
                                                      Btl + 16384, b3, Ws4, Wn4,
                                                      sbuf, gbuf, N);

    // ---- layer 4 (64->1): scalar CSR gather + sigmoid ----
    final_kernel<<<gridN, BT, 0, stream>>>(sbuf, dinv, gbuf, off, offe, col, b4, out, N);
}

// Round 15
// 404.856 us; speedup vs baseline: 1.0992x; 1.0272x over previous
//
#include <hip/hip_runtime.h>
#include <hip/hip_bf16.h>
#include <math.h>

// ---------------------------------------------------------------------------
// ActorGNN: 4-layer GraphConv. R15:
//  - bucketCSR parallelism fix: BKT_SHIFT 9->7 (128-node buckets, 782 blocks
//    vs 196 = 0.77/CU). R12/R14 accounting shows ~35us hiding in the CSR
//    scatter; 196-block kernel with serial LDS-atomic work is the suspect.
//  - bins pack: (dstLocal<<24)|src. binA 256 blocks (32B runs/bucket/block).
//  - split_x merged into prep kernel (disjoint block ranges): 10 dispatches.
//  - layers split (R14 form): gather 52us @3.2TB/s + dense MFMA ~18us.
// ---------------------------------------------------------------------------

using bfrag = __attribute__((ext_vector_type(8))) short;   // 8 bf16 (4 VGPR)
using ffrag = __attribute__((ext_vector_type(4))) float;   // 4 fp32 acc

#define BKT_SHIFT 7                 // 128 nodes per bucket
#define BKT_NODES (1 << BKT_SHIFT)

__device__ __forceinline__ int load_idx32(const int* __restrict__ ei32, int is64,
                                          long long pos) {
    return is64 ? ei32[2 * pos] : ei32[pos];
}

__device__ __forceinline__ unsigned short f2b_rne(float f) {
    union { float f; unsigned u; } c;
    c.f = f;
    unsigned r = c.u + 0x7FFFu + ((c.u >> 16) & 1u);
    return (unsigned short)(r >> 16);
}

__device__ __forceinline__ float b2f(unsigned short u) {
    union { unsigned u; float f; } c;
    c.u = ((unsigned)u) << 16;
    return c.f;
}

// ---- prep: weight B^T hi/lo (3 layers) + bktc zero + int64 detect + x->bf16
__global__ void prep_kernel(
    const float* __restrict__ Ws1, const float* __restrict__ Wn1,
    const float* __restrict__ Ws2, const float* __restrict__ Wn2,
    const float* __restrict__ Ws3, const float* __restrict__ Wn3,
    unsigned short* __restrict__ bthi, unsigned short* __restrict__ btlo,
    const int* __restrict__ ei, int* __restrict__ bktc, int* __restrict__ flag,
    const float4* __restrict__ x4, ushort4* __restrict__ hi4, int n4) {
    int bid = blockIdx.x;
    if (bid < 96) {
        if (bid < 4) bktc[bid * 256 + threadIdx.x] = 0;
        if (bid == 0 && threadIdx.x == 0) {
            int allz = 1;
            for (int i = 0; i < 32; ++i)
                if (ei[2 * i + 1] != 0) allz = 0;
            *flag = allz;
        }
        int i = bid * 256 + threadIdx.x;
        if (i < 3 * 8192) {
            int layer = i >> 13;
            int j = i & 8191;
            int n = j >> 7, k = j & 127;
            const float* Ws = layer == 0 ? Ws1 : (layer == 1 ? Ws2 : Ws3);
            const float* Wn = layer == 0 ? Wn1 : (layer == 1 ? Wn2 : Wn3);
            float v = (k < 64) ? Ws[k * 64 + n] : Wn[(k - 64) * 64 + n];
            unsigned short hi = f2b_rne(v);
            bthi[i] = hi;
            btlo[i] = f2b_rne(v - b2f(hi));
        }
    } else {
        int i = (bid - 96) * 256 + threadIdx.x;
        if (i < n4) {
            float4 v = x4[i];
            ushort4 h;
            h.x = f2b_rne(v.x); h.y = f2b_rne(v.y);
            h.z = f2b_rne(v.z); h.w = f2b_rne(v.w);
            hi4[i] = h;
        }
    }
}

// ---- PassA: bin edges into dst-buckets, packed (dstLocal<<24 | src) ----
__global__ __launch_bounds__(256) void binA_kernel(
    const int* __restrict__ ei32, const int* __restrict__ flagp,
    int* __restrict__ bktCnt, unsigned* __restrict__ bins, int E, int nbkt,
    int cap, int chunksz) {
    __shared__ int cnt[1024];
    __shared__ int base[1024];
    int is64 = *flagp;
    int elo = blockIdx.x * chunksz;
    int ehi = min(E, elo + chunksz);
    if (elo >= E) return;
    for (int i = threadIdx.x; i < nbkt; i += 256) cnt[i] = 0;
    __syncthreads();
    for (int e = elo + (int)threadIdx.x; e < ehi; e += 256) {
        int dst = load_idx32(ei32, is64, (long long)E + e);
        atomicAdd(&cnt[dst >> BKT_SHIFT], 1);
    }
    __syncthreads();
    for (int i = threadIdx.x; i < nbkt; i += 256) {
        base[i] = atomicAdd(&bktCnt[i], cnt[i]);
        cnt[i] = 0;
    }
    __syncthreads();
    for (int e = elo + (int)threadIdx.x; e < ehi; e += 256) {
        int dst = load_idx32(ei32, is64, (long long)E + e);
        int src = load_idx32(ei32, is64, e);
        int b = dst >> BKT_SHIFT;
        int r = atomicAdd(&cnt[b], 1);
        bins[(size_t)b * cap + base[b] + r] =
            ((unsigned)(dst & (BKT_NODES - 1)) << 24) | (unsigned)src;
    }
}

// ---- bucketCSR: degree + 128-wide scan + scatter + dinv, one kernel ----
// col is bucket-local: node n in bucket b has edges at [off[n], offe[n]).
__global__ __launch_bounds__(256) void bucketCSR_kernel(
    const int* __restrict__ bktCnt, const unsigned* __restrict__ bins,
    int* __restrict__ off, int* __restrict__ offe, int* __restrict__ col,
    float* __restrict__ dinv, int N, int cap) {
    __shared__ int deg[BKT_NODES];
    __shared__ int loc[BKT_NODES];
    __shared__ int ssum[BKT_NODES];
    int b = blockIdx.x;
    int lo = b << BKT_SHIFT;
    int n = min(BKT_NODES, N - lo);
    int t = threadIdx.x;
    if (t < BKT_NODES) deg[t] = 0;
    __syncthreads();
    int cnt = bktCnt[b];
    const unsigned* bb = bins + (size_t)b * cap;
    for (int i = t; i < cnt; i += 256)
        atomicAdd(&deg[bb[i] >> 24], 1);
    __syncthreads();
    if (t < BKT_NODES) ssum[t] = deg[t];
    __syncthreads();
    for (int o = 1; o < BKT_NODES; o <<= 1) {
        int v = (t >= o && t < BKT_NODES) ? ssum[t - o] : 0;
        __syncthreads();
        if (t < BKT_NODES) ssum[t] += v;
        __syncthreads();
    }
    if (t < BKT_NODES) loc[t] = ssum[t] - deg[t];
    __syncthreads();
    int base = b * cap;
    if (t < n) {
        int d = deg[t];
        off[lo + t] = base + loc[t];
        offe[lo + t] = base + loc[t] + d;
        dinv[lo + t] = 1.0f / fmaxf((float)d, 1.0f);
    }
    __syncthreads();
    for (int i = t; i < cnt; i += 256) {
        unsigned p = bb[i];
        int pos = atomicAdd(&loc[p >> 24], 1);
        col[base + pos] = (int)(p & 0xFFFFFFu);
    }
}

// wave per node; lane = g*16 + t: edge-group g (0..3), dims t*4..t*4+3.
// Reads bf16-hi rows (128B); emits mean-scaled agg as bf16 hi.
__global__ __launch_bounds__(256) void gather64_b16_kernel(
    const unsigned short* __restrict__ hb, const int* __restrict__ off,
    const int* __restrict__ offe, const int* __restrict__ col,
    const float* __restrict__ dinv, unsigned short* __restrict__ ghi, int N) {
    int wave = threadIdx.x >> 6;
    int lane = threadIdx.x & 63;
    int g = lane >> 4;
    int t = lane & 15;
    int n = blockIdx.x * 4 + wave;
    if (n >= N) return;
    int e = off[n], end = offe[n];
    float4 a0 = make_float4(0.f, 0.f, 0.f, 0.f);
    float4 a1 = make_float4(0.f, 0.f, 0.f, 0.f);
    float4 a2 = make_float4(0.f, 0.f, 0.f, 0.f);
    float4 a3 = make_float4(0.f, 0.f, 0.f, 0.f);
    for (; e + 16 <= end; e += 16) {
        int s0 = col[e + g];
        int s1 = col[e + 4 + g];
        int s2 = col[e + 8 + g];
        int s3 = col[e + 12 + g];
        ushort4 u0 = *(const ushort4*)&hb[(size_t)s0 * 64 + t * 4];
        ushort4 u1 = *(const ushort4*)&hb[(size_t)s1 * 64 + t * 4];
        ushort4 u2 = *(const ushort4*)&hb[(size_t)s2 * 64 + t * 4];
        ushort4 u3 = *(const ushort4*)&hb[(size_t)s3 * 64 + t * 4];
        a0.x += b2f(u0.x); a0.y += b2f(u0.y); a0.z += b2f(u0.z); a0.w += b2f(u0.w);
        a1.x += b2f(u1.x); a1.y += b2f(u1.y); a1.z += b2f(u1.z); a1.w += b2f(u1.w);
        a2.x += b2f(u2.x); a2.y += b2f(u2.y); a2.z += b2f(u2.z); a2.w += b2f(u2.w);
        a3.x += b2f(u3.x); a3.y += b2f(u3.y); a3.z += b2f(u3.z); a3.w += b2f(u3.w);
    }
    for (; e + 8 <= end; e += 8) {
        int s0 = col[e + g];
        int s1 = col[e + 4 + g];
        ushort4 u0 = *(const ushort4*)&hb[(size_t)s0 * 64 + t * 4];
        ushort4 u1 = *(const ushort4*)&hb[(size_t)s1 * 64 + t * 4];
        a0.x += b2f(u0.x); a0.y += b2f(u0.y); a0.z += b2f(u0.z); a0.w += b2f(u0.w);
        a1.x += b2f(u1.x); a1.y += b2f(u1.y); a1.z += b2f(u1.z); a1.w += b2f(u1.w);
    }
    for (; e < end; e += 4) {
        if (e + g < end) {
            int s0 = col[e + g];
            ushort4 u0 = *(const ushort4*)&hb[(size_t)s0 * 64 + t * 4];
            a2.x += b2f(u0.x); a2.y += b2f(u0.y); a2.z += b2f(u0.z); a2.w += b2f(u0.w);
        }
    }
    float4 acc;
    acc.x = (a0.x + a1.x) + (a2.x + a3.x);
    acc.y = (a0.y + a1.y) + (a2.y + a3.y);
    acc.z = (a0.z + a1.z) + (a2.z + a3.z);
    acc.w = (a0.w + a1.w) + (a2.w + a3.w);
#pragma unroll
    for (int m = 16; m <= 32; m <<= 1) {
        acc.x += __shfl_xor(acc.x, m, 64);
        acc.y += __shfl_xor(acc.y, m, 64);
        acc.z += __shfl_xor(acc.z, m, 64);
        acc.w += __shfl_xor(acc.w, m, 64);
    }
    if (g == 0) {
        float di = dinv[n];
        ushort4 h;
        h.x = f2b_rne(acc.x * di);
        h.y = f2b_rne(acc.y * di);
        h.z = f2b_rne(acc.z * di);
        h.w = f2b_rne(acc.w * di);
        *(ushort4*)&ghi[(size_t)n * 64 + t * 4] = h;
    }
}

// MFMA dense: D = relu([h|agg] @ [Ws;Wn] + b). hi-only inputs; weights hi/lo.
__global__ __launch_bounds__(256) void dense_mfma_kernel(
    const unsigned short* __restrict__ Hhi, const unsigned short* __restrict__ Ghi,
    const unsigned short* __restrict__ Bthi, const unsigned short* __restrict__ Btlo,
    const float* __restrict__ b, unsigned short* __restrict__ Dhi, int N) {
    int lane = threadIdx.x & 63;
    int m = lane & 15, quad = lane >> 4;
    int wid = (blockIdx.x * blockDim.x + threadIdx.x) >> 6;
    int nw = (gridDim.x * blockDim.x) >> 6;
    bfrag bhi[4][4];
#pragma unroll
    for (int t = 0; t < 4; ++t)
#pragma unroll
        for (int c = 0; c < 4; ++c)
            bhi[t][c] = *(const bfrag*)(Bthi + (size_t)(t * 16 + m) * 128 + c * 32 + quad * 8);
    float bl[4];
#pragma unroll
    for (int t = 0; t < 4; ++t) bl[t] = b[t * 16 + m];
    int ngroups = (N + 15) >> 4;
    for (int g = wid; g < ngroups; g += nw) {
        int n0 = g << 4;
        int nr = n0 + m;
        if (nr > N - 1) nr = N - 1;
        const unsigned short* hrow = Hhi + (size_t)nr * 64 + quad * 8;
        const unsigned short* grow = Ghi + (size_t)nr * 64 + quad * 8;
        bfrag ah[4];
        ah[0] = *(const bfrag*)(hrow);
        ah[1] = *(const bfrag*)(hrow + 32);
        ah[2] = *(const bfrag*)(grow);
        ah[3] = *(const bfrag*)(grow + 32);
#pragma unroll
        for (int t = 0; t < 4; ++t) {
            ffrag acc = {bl[t], bl[t], bl[t], bl[t]};
#pragma unroll
            for (int c = 0; c < 4; ++c) {
                bfrag blo = *(const bfrag*)(Btlo + (size_t)(t * 16 + m) * 128 + c * 32 + quad * 8);
                acc = __builtin_amdgcn_mfma_f32_16x16x32_bf16(ah[c], bhi[t][c], acc, 0, 0, 0);
                acc = __builtin_amdgcn_mfma_f32_16x16x32_bf16(ah[c], blo, acc, 0, 0, 0);
            }
#pragma unroll
            for (int r = 0; r < 4; ++r) {
                int node = n0 + quad * 4 + r;
                if (node < N)
                    Dhi[(size_t)node * 64 + t * 16 + m] = f2b_rne(fmaxf(acc[r], 0.f));
            }
        }
    }
}

// Layer-3 dense with fused layer-4 pre-transform (s,g from fp32 accs).
__global__ __launch_bounds__(256) void dense_mfma_last_kernel(
    const unsigned short* __restrict__ Hhi, const unsigned short* __restrict__ Ghi,
    const unsigned short* __restrict__ Bthi, const unsigned short* __restrict__ Btlo,
    const float* __restrict__ b, const float* __restrict__ Ws4,
    const float* __restrict__ Wn4, float* __restrict__ sbuf,
    float* __restrict__ gbuf, int N) {
    int lane = threadIdx.x & 63;
    int m = lane & 15, quad = lane >> 4;
    int wid = (blockIdx.x * blockDim.x + threadIdx.x) >> 6;
    int nw = (gridDim.x * blockDim.x) >> 6;
    bfrag bhi[4][4];
#pragma unroll
    for (int t = 0; t < 4; ++t)
#pragma unroll
        for (int c = 0; c < 4; ++c)
            bhi[t][c] = *(const bfrag*)(Bthi + (size_t)(t * 16 + m) * 128 + c * 32 + quad * 8);
    float bl[4], w4s[4], w4n[4];
#pragma unroll
    for (int t = 0; t < 4; ++t) {
        bl[t] = b[t * 16 + m];
        w4s[t] = Ws4[t * 16 + m];
        w4n[t] = Wn4[t * 16 + m];
    }
    int ngroups = (N + 15) >> 4;
    for (int g = wid; g < ngroups; g += nw) {
        int n0 = g << 4;
        int nr = n0 + m;
        if (nr > N - 1) nr = N - 1;
        const unsigned short* hrow = Hhi + (size_t)nr * 64 + quad * 8;
        const unsigned short* grow = Ghi + (size_t)nr * 64 + quad * 8;
        bfrag ah[4];
        ah[0] = *(const bfrag*)(hrow);
        ah[1] = *(const bfrag*)(hrow + 32);
        ah[2] = *(const bfrag*)(grow);
        ah[3] = *(const bfrag*)(grow + 32);
        ffrag accs[4];
#pragma unroll
        for (int t = 0; t < 4; ++t) {
            ffrag acc = {bl[t], bl[t], bl[t], bl[t]};
#pragma unroll
            for (int c = 0; c < 4; ++c) {
                bfrag blo = *(const bfrag*)(Btlo + (size_t)(t * 16 + m) * 128 + c * 32 + quad * 8);
                acc = __builtin_amdgcn_mfma_f32_16x16x32_bf16(ah[c], bhi[t][c], acc, 0, 0, 0);
                acc = __builtin_amdgcn_mfma_f32_16x16x32_bf16(ah[c], blo, acc, 0, 0, 0);
            }
            accs[t] = acc;
        }
#pragma unroll
        for (int r = 0; r < 4; ++r) {
            float ps = 0.f, pg = 0.f;
#pragma unroll
            for (int t = 0; t < 4; ++t) {
                float v = fmaxf(accs[t][r], 0.f);
                ps = fmaf(v, w4s[t], ps);
                pg = fmaf(v, w4n[t], pg);
            }
#pragma unroll
            for (int mask = 1; mask <= 8; mask <<= 1) {
                ps += __shfl_xor(ps, mask, 64);
                pg += __shfl_xor(pg, mask, 64);
            }
            int node = n0 + quad * 4 + r;
            if (m == 0 && node < N) {
                sbuf[node] = ps;
                gbuf[node] = pg;
            }
        }
    }
}

// thread per node: scalar CSR gather of g (400 KB, L2-resident) + sigmoid
__global__ void final_kernel(const float* __restrict__ s, const float* __restrict__ dinv,
                             const float* __restrict__ g, const int* __restrict__ off,
                             const int* __restrict__ offe, const int* __restrict__ col,
                             const float* __restrict__ b4, float* __restrict__ out, int N) {
    int n = blockIdx.x * blockDim.x + threadIdx.x;
    if (n >= N) return;
    float a = 0.f;
    int e = off[n], end = offe[n];
    for (; e < end; ++e) a += g[col[e]];
    float z = s[n] + dinv[n] * a + b4[0];
    out[n] = 1.0f / (1.0f + expf(-z));
}

static inline int cdiv(long long a, long long b) { return (int)((a + b - 1) / b); }

extern "C" void kernel_launch(void* const* d_in, const int* in_sizes, int n_in,
                              void* d_out, int out_size, void* d_ws, size_t ws_size,
                              hipStream_t stream) {
    const float* x   = (const float*)d_in[0];
    const int*   ei  = (const int*)d_in[1];
    const float* Ws1 = (const float*)d_in[2];
    const float* Wn1 = (const float*)d_in[3];
    const float* b1  = (const float*)d_in[4];
    const float* Ws2 = (const float*)d_in[5];
    const float* Wn2 = (const float*)d_in[6];
    const float* b2  = (const float*)d_in[7];
    const float* Ws3 = (const float*)d_in[8];
    const float* Wn3 = (const float*)d_in[9];
    const float* b3  = (const float*)d_in[10];
    const float* Ws4 = (const float*)d_in[11];
    const float* Wn4 = (const float*)d_in[12];
    const float* b4  = (const float*)d_in[13];
    float* out = (float*)d_out;

    const int N = in_sizes[0] / 64;
    const int E = in_sizes[1] / 2;

    const int nbkt = cdiv(N, BKT_NODES);                 // <=1024 for N<=131072
    const int cap  = E / nbkt + E / nbkt / 8 + 64;       // ~12.5% + 64 margin

    // workspace layout
    unsigned* bins = (unsigned*)d_ws;                    // nbkt*cap
    int* col = (int*)(bins + (size_t)nbkt * cap);        // nbkt*cap (bucket-local)
    unsigned short* HhiA = (unsigned short*)(col + (size_t)nbkt * cap);  // N*64
    unsigned short* HhiB = HhiA + (size_t)N * 64;        // N*64
    unsigned short* Ghi  = HhiB + (size_t)N * 64;        // N*64
    unsigned short* Bth  = Ghi + (size_t)N * 64;         // 3*8192
    unsigned short* Btl  = Bth + 3 * 8192;               // 3*8192
    float* dinv = (float*)(Btl + 3 * 8192);              // N
    float* sbuf = dinv + N;                              // N
    float* gbuf = sbuf + N;                              // N
    int*   off  = (int*)(gbuf + N);                      // N
    int*   offe = off + N;                               // N
    int*   bktc = offe + N;                              // 1024
    int*   flag = bktc + 1024;                           // 1

    const int BT = 256;
    const int gridN  = cdiv(N, BT);
    const int gridNd = cdiv(N, 4);                       // gather: wave/node
    const int gridMM = cdiv(cdiv(N, 16), 4);             // dense: 4 waves/block
    const int binBlocks = 256;
    const int chunksz = cdiv(E, binBlocks);
    const int gridPrep = 96 + cdiv((long long)N * 16, BT);

    // ---- prep: weights + init + x->bf16 (one kernel) ----
    prep_kernel<<<gridPrep, BT, 0, stream>>>(Ws1, Wn1, Ws2, Wn2, Ws3, Wn3,
                                             Bth, Btl, ei, bktc, flag,
                                             (const float4*)x, (ushort4*)HhiA, N * 16);

    // ---- CSR build: 2 kernels ----
    binA_kernel<<<binBlocks, BT, 0, stream>>>(ei, flag, bktc, bins, E, nbkt, cap, chunksz);
    bucketCSR_kernel<<<nbkt, BT, 0, stream>>>(bktc, bins, off, offe, col, dinv, N, cap);

    // ---- layer 1 ----
    gather64_b16_kernel<<<gridNd, BT, 0, stream>>>(HhiA, off, offe, col, dinv, Ghi, N);
    dense_mfma_kernel<<<gridMM, BT, 0, stream>>>(HhiA, Ghi, Bth, Btl, b1, HhiB, N);

    // ---- layer 2 ----
    gather64_b16_kernel<<<gridNd, BT, 0, stream>>>(HhiB, off, offe, col, dinv, Ghi, N);
    dense_mfma_kernel<<<gridMM, BT, 0, stream>>>(HhiB, Ghi, Bth + 8192, Btl + 8192,
                                                 b2, HhiA, N);

    // ---- layer 3 + fused layer-4 pre-transform ----
    gather64_b16_kernel<<<gridNd, BT, 0, stream>>>(HhiA, off, offe, col, dinv, Ghi, N);
    dense_mfma_last_kernel<<<gridMM, BT, 0, stream>>>(HhiA, Ghi, Bth + 16384,
                                                      Btl + 16384, b3, Ws4, Wn4,
                                                      sbuf, gbuf, N);

    // ---- layer 4 (64->1): scalar CSR gather + sigmoid ----
    final_kernel<<<gridN, BT, 0, stream>>>(sbuf, dinv, gbuf, off, offe, col, b4, out, N);
}